// Round 9
// baseline (121.437 us; speedup 1.0000x reference)
//
#include <hip/hip_runtime.h>
#include <hip/hip_cooperative_groups.h>
#include <math.h>

namespace cg = cooperative_groups;

// out[t,b] = F(x[t,b]) — scalar function (zero-state LSTM cell x2 + linear).
// Build F-table (16384 entries over [-10,10]) each launch, then lerp.
//
// R9: fuse build+lookup into ONE cooperative kernel (256 blocks x 1024 = 1
// block/CU, co-resident) with a single grid.sync() between table-write and
// lookup — removes 1 launch + 2 stream-drain boundaries (~3-4us of the ~14us
// controllable slice). grid.sync provides the device-scope fence for
// cross-XCD table visibility. Build phase = R5/R8 structure verbatim (best
// measured; R6/R7 showed contiguous-record chains regress ~3us vs 12
// independent s_load streams). Repack stays separate: s_load consumers get
// coherence free at the kernel boundary.

#define NTAB 16384
#define XMIN (-10.0f)
#define XMAX (10.0f)

typedef _Float16 h2_t __attribute__((ext_vector_type(2)));

__device__ __forceinline__ float fexp2_(float x) { return __builtin_amdgcn_exp2f(x); }
__device__ __forceinline__ float frcp_(float x)  { return __builtin_amdgcn_rcpf(x); }
// sigmoid(z) = 1/(1+2^(-z*log2 e)) ; tanh(z) = 1 - 2/(1+2^(2z*log2 e))
__device__ __forceinline__ float fsig_(float z)  { return frcp_(1.0f + fexp2_(-1.44269504f * z)); }
__device__ __forceinline__ float ftanh_(float z) { return 1.0f - 2.0f * frcp_(1.0f + fexp2_(2.88539008f * z)); }

// Live rows of w_ih2 (torch gate order i,f,g,o; f dead since c_prev=0):
// packed row r: r in [0,51) = i-gate j=r ; [51,102) = g-gate ; [102,153) = o-gate.
__global__ __launch_bounds__(256) void repack(
    const float* __restrict__ w_ih2, const float* __restrict__ b_ih2,
    const float* __restrict__ b_hh2, unsigned int* __restrict__ Wp,
    float* __restrict__ B2)
{
    int g = blockIdx.x * 256 + threadIdx.x;
    if (g < 153 * 26) {
        int r = g / 26;
        int p = g - r * 26;
        int src = (r < 51) ? r : r + 51;
        float a = w_ih2[src * 51 + 2 * p];
        float b = (2 * p + 1 < 51) ? w_ih2[src * 51 + 2 * p + 1] : 0.0f;
        h2_t h;
        h.x = (_Float16)a;   // RTE via v_cvt_f16_f32 (not pkrtz/RTZ: unbiased)
        h.y = (_Float16)b;
        Wp[r * 26 + p] = __builtin_bit_cast(unsigned int, h);
    }
    if (g < 153) {
        int src = (g < 51) ? g : g + 51;
        B2[g] = b_ih2[src] + b_hh2[src];
    }
}

__device__ __forceinline__ float lerp_tab(float x, const float* __restrict__ t) {
    const float inv_h = (float)(NTAB - 1) / (XMAX - XMIN);
    float u = (x - XMIN) * inv_h;
    u = fminf(fmaxf(u, 0.0f), (float)(NTAB - 1) - 0.001f);
    int   i0 = (int)u;
    float f  = u - (float)i0;
    float t0 = t[i0];
    float t1 = t[i0 + 1];
    return fmaf(f, t1 - t0, t0);
}

__global__ __launch_bounds__(1024, 4) void fused_build_lookup(
    const float* __restrict__ w_ih1, const float* __restrict__ b_ih1, const float* __restrict__ b_hh1,
    const unsigned int* __restrict__ Wp, const float* __restrict__ B2,
    const float* __restrict__ w_lin, const float* __restrict__ b_lin,
    float* __restrict__ table, const float* __restrict__ x, float* __restrict__ outp, int n)
{
    __shared__ float h1s[51][64];     // h1 shared across waves: [j][lane] conflict-free
    __shared__ float sPart[16][64];

    const int tid  = threadIdx.x;
    const int lane = tid & 63;
    // readfirstlane: wave id provably uniform -> weight addresses scalarize to s_load.
    const int wave = __builtin_amdgcn_readfirstlane(tid >> 6);

    const int   e  = blockIdx.x * 64 + lane;         // 256 blocks x 64 entries = NTAB
    const float xe = XMIN + (XMAX - XMIN) * ((float)e / (float)(NTAB - 1));

    // ---- Phase 1: layer-1 once per block, j-rows split over 16 waves ----
    for (int j = wave; j < 51; j += 16) {
        float gi = fmaf(xe, w_ih1[j],       b_ih1[j]       + b_hh1[j]);
        float gg = fmaf(xe, w_ih1[j + 102], b_ih1[j + 102] + b_hh1[j + 102]);
        float go = fmaf(xe, w_ih1[j + 153], b_ih1[j + 153] + b_hh1[j + 153]);
        float c  = fsig_(gi) * ftanh_(gg);
        h1s[j][lane] = fsig_(go) * ftanh_(c);
    }
    __syncthreads();

    // ---- Pack this lane's h1 vector to f16 pairs (26 VGPRs) ----
    h2_t h1p[26];
    #pragma unroll
    for (int p = 0; p < 26; ++p) {
        float a = h1s[2 * p][lane];
        float b = (2 * p + 1 < 51) ? h1s[2 * p + 1][lane] : 0.0f;
        h2_t h;
        h.x = (_Float16)a;
        h.y = (_Float16)b;
        h1p[p] = h;
    }

    // ---- Phase 2: each wave does 3-4 rows via v_dot2_f32_f16 ----
    float part = 0.0f;
    for (int j = wave; j < 51; j += 16) {
        const unsigned int* __restrict__ Wi = Wp + j * 26;
        const unsigned int* __restrict__ Wg = Wp + (51 + j) * 26;
        const unsigned int* __restrict__ Wo = Wp + (102 + j) * 26;
        float gi = B2[j];
        float gg = B2[51 + j];
        float go = B2[102 + j];
        #pragma unroll
        for (int p = 0; p < 26; ++p) {
            gi = __builtin_amdgcn_fdot2(h1p[p], __builtin_bit_cast(h2_t, Wi[p]), gi, false);
            gg = __builtin_amdgcn_fdot2(h1p[p], __builtin_bit_cast(h2_t, Wg[p]), gg, false);
            go = __builtin_amdgcn_fdot2(h1p[p], __builtin_bit_cast(h2_t, Wo[p]), go, false);
        }
        float c2  = fsig_(gi) * ftanh_(gg);
        float h2v = fsig_(go) * ftanh_(c2);
        part = fmaf(h2v, w_lin[j], part);
    }

    sPart[wave][lane] = part;
    __syncthreads();
    if (wave == 0) {
        float tv = b_lin[0];
        #pragma unroll
        for (int w = 0; w < 16; ++w) tv += sPart[w][lane];
        table[e] = tv;
    }

    // ---- Device-scope barrier: table fully written & visible cross-XCD ----
    cg::this_grid().sync();

    // ---- Phase 3: lookup (1 float4 per thread; 102400 f4 < 262144 threads) ----
    int i4 = blockIdx.x * 1024 + tid;
    if (i4 < (n >> 2)) {
        float4 xv = ((const float4*)x)[i4];
        float4 r;
        r.x = lerp_tab(xv.x, table);
        r.y = lerp_tab(xv.y, table);
        r.z = lerp_tab(xv.z, table);
        r.w = lerp_tab(xv.w, table);
        ((float4*)outp)[i4] = r;
    }
}

extern "C" void kernel_launch(void* const* d_in, const int* in_sizes, int n_in,
                              void* d_out, int out_size, void* d_ws, size_t ws_size,
                              hipStream_t stream) {
    const float* x     = (const float*)d_in[0];
    const float* w_ih1 = (const float*)d_in[1];
    // d_in[2] = w_hh1 (unused: h_prev = 0)
    const float* b_ih1 = (const float*)d_in[3];
    const float* b_hh1 = (const float*)d_in[4];
    const float* w_ih2 = (const float*)d_in[5];
    // d_in[6] = w_hh2 (unused)
    const float* b_ih2 = (const float*)d_in[7];
    const float* b_hh2 = (const float*)d_in[8];
    const float* w_lin = (const float*)d_in[9];
    const float* b_lin = (const float*)d_in[10];

    float* outp = (float*)d_out;
    // d_ws layout (dwords): [0,16384) table | [16384,+3978) packed W2 | then 153 bias sums
    float*        table = (float*)d_ws;
    unsigned int* Wp    = (unsigned int*)d_ws + 16384;
    float*        B2    = (float*)d_ws + 16384 + 153 * 26;
    int n = in_sizes[0];     // T*B = 409600 (divisible by 4)

    repack<<<(153 * 26 + 255) / 256, 256, 0, stream>>>(w_ih2, b_ih2, b_hh2, Wp, B2);

    void* args[] = {
        (void*)&w_ih1, (void*)&b_ih1, (void*)&b_hh1,
        (void*)&Wp, (void*)&B2, (void*)&w_lin, (void*)&b_lin,
        (void*)&table, (void*)&x, (void*)&outp, (void*)&n
    };
    hipLaunchCooperativeKernel((void*)fused_build_lookup,
                               dim3(NTAB / 64), dim3(1024), args, 0, stream);
}

// Round 10
// 84.894 us; speedup vs baseline: 1.4305x; 1.4305x over previous
//
#include <hip/hip_runtime.h>
#include <math.h>

// out[t,b] = F(x[t,b]) — scalar function (zero-state LSTM cell x2 + linear).
// Build F-table (16384 entries over [-10,10]) each launch, then lerp.
//
// R10: revert to R8/R5 exactly (best measured 84.2/84.9us). R9's cooperative
// build+lookup fusion cost +36.5us (cooperative launch has no cheap graph-
// replay path; grid.sync serializes lookup behind the slowest build block).
// Ledger: ~71us fixed harness reset (268MB d_ws poison @85% HBM + ~30us
// restores) + ~13us kernels (repack ~2, build ~7 latency-bound single-block
// critical path, lookup ~3.5). Measured-out levers: occupancy (R3/R6), dedup
// (R4), f16 scalar stream (R5), record layout (R6/R7: -3us regression),
// prefetch (R7: no-op), cooperative fusion (R9: -36us regression).

#define NTAB 16384
#define XMIN (-10.0f)
#define XMAX (10.0f)

typedef _Float16 h2_t __attribute__((ext_vector_type(2)));

__device__ __forceinline__ float fexp2_(float x) { return __builtin_amdgcn_exp2f(x); }
__device__ __forceinline__ float frcp_(float x)  { return __builtin_amdgcn_rcpf(x); }
// sigmoid(z) = 1/(1+2^(-z*log2 e)) ; tanh(z) = 1 - 2/(1+2^(2z*log2 e))
__device__ __forceinline__ float fsig_(float z)  { return frcp_(1.0f + fexp2_(-1.44269504f * z)); }
__device__ __forceinline__ float ftanh_(float z) { return 1.0f - 2.0f * frcp_(1.0f + fexp2_(2.88539008f * z)); }

// Live rows of w_ih2 (torch gate order i,f,g,o; f dead since c_prev=0):
// packed row r: r in [0,51) = i-gate j=r ; [51,102) = g-gate ; [102,153) = o-gate.
__global__ __launch_bounds__(256) void repack(
    const float* __restrict__ w_ih2, const float* __restrict__ b_ih2,
    const float* __restrict__ b_hh2, unsigned int* __restrict__ Wp,
    float* __restrict__ B2)
{
    int g = blockIdx.x * 256 + threadIdx.x;
    if (g < 153 * 26) {
        int r = g / 26;
        int p = g - r * 26;
        int src = (r < 51) ? r : r + 51;
        float a = w_ih2[src * 51 + 2 * p];
        float b = (2 * p + 1 < 51) ? w_ih2[src * 51 + 2 * p + 1] : 0.0f;
        h2_t h;
        h.x = (_Float16)a;   // RTE via v_cvt_f16_f32 (not pkrtz/RTZ: unbiased)
        h.y = (_Float16)b;
        Wp[r * 26 + p] = __builtin_bit_cast(unsigned int, h);
    }
    if (g < 153) {
        int src = (g < 51) ? g : g + 51;
        B2[g] = b_ih2[src] + b_hh2[src];
    }
}

__global__ __launch_bounds__(1024, 4) void build_table(
    const float* __restrict__ w_ih1, const float* __restrict__ b_ih1, const float* __restrict__ b_hh1,
    const unsigned int* __restrict__ Wp, const float* __restrict__ B2,
    const float* __restrict__ w_lin, const float* __restrict__ b_lin,
    float* __restrict__ table)
{
    __shared__ float h1s[51][64];     // h1 shared across waves: [j][lane] conflict-free
    __shared__ float sPart[16][64];

    const int tid  = threadIdx.x;
    const int lane = tid & 63;
    // readfirstlane: wave id provably uniform -> weight addresses scalarize to s_load.
    const int wave = __builtin_amdgcn_readfirstlane(tid >> 6);

    const int   e = blockIdx.x * 64 + lane;          // 256 blocks x 64 entries = NTAB
    const float x = XMIN + (XMAX - XMIN) * ((float)e / (float)(NTAB - 1));

    // ---- Phase 1: layer-1 once per block, j-rows split over 16 waves ----
    for (int j = wave; j < 51; j += 16) {
        float gi = fmaf(x, w_ih1[j],       b_ih1[j]       + b_hh1[j]);
        float gg = fmaf(x, w_ih1[j + 102], b_ih1[j + 102] + b_hh1[j + 102]);
        float go = fmaf(x, w_ih1[j + 153], b_ih1[j + 153] + b_hh1[j + 153]);
        float c  = fsig_(gi) * ftanh_(gg);
        h1s[j][lane] = fsig_(go) * ftanh_(c);
    }
    __syncthreads();

    // ---- Pack this lane's h1 vector to f16 pairs (26 VGPRs) ----
    h2_t h1p[26];
    #pragma unroll
    for (int p = 0; p < 26; ++p) {
        float a = h1s[2 * p][lane];
        float b = (2 * p + 1 < 51) ? h1s[2 * p + 1][lane] : 0.0f;
        h2_t h;
        h.x = (_Float16)a;
        h.y = (_Float16)b;
        h1p[p] = h;
    }

    // ---- Phase 2: each wave does 3-4 rows via v_dot2_f32_f16 ----
    float part = 0.0f;
    for (int j = wave; j < 51; j += 16) {
        const unsigned int* __restrict__ Wi = Wp + j * 26;
        const unsigned int* __restrict__ Wg = Wp + (51 + j) * 26;
        const unsigned int* __restrict__ Wo = Wp + (102 + j) * 26;
        float gi = B2[j];
        float gg = B2[51 + j];
        float go = B2[102 + j];
        #pragma unroll
        for (int p = 0; p < 26; ++p) {
            gi = __builtin_amdgcn_fdot2(h1p[p], __builtin_bit_cast(h2_t, Wi[p]), gi, false);
            gg = __builtin_amdgcn_fdot2(h1p[p], __builtin_bit_cast(h2_t, Wg[p]), gg, false);
            go = __builtin_amdgcn_fdot2(h1p[p], __builtin_bit_cast(h2_t, Wo[p]), go, false);
        }
        float c2  = fsig_(gi) * ftanh_(gg);
        float h2v = fsig_(go) * ftanh_(c2);
        part = fmaf(h2v, w_lin[j], part);
    }

    sPart[wave][lane] = part;
    __syncthreads();
    if (wave == 0) {
        float out = b_lin[0];
        #pragma unroll
        for (int w = 0; w < 16; ++w) out += sPart[w][lane];
        table[e] = out;
    }
}

__device__ __forceinline__ float lerp_tab(float x, const float* __restrict__ t) {
    const float inv_h = (float)(NTAB - 1) / (XMAX - XMIN);
    float u = (x - XMIN) * inv_h;
    u = fminf(fmaxf(u, 0.0f), (float)(NTAB - 1) - 0.001f);
    int   i0 = (int)u;
    float f  = u - (float)i0;
    float t0 = t[i0];
    float t1 = t[i0 + 1];
    return fmaf(f, t1 - t0, t0);
}

__global__ __launch_bounds__(256) void lookup_kernel(
    const float* __restrict__ x, const float* __restrict__ table,
    float* __restrict__ out, int n)
{
    int i4 = blockIdx.x * 256 + threadIdx.x;
    int base = i4 * 4;
    if (base + 3 < n) {
        float4 xv = ((const float4*)x)[i4];
        float4 r;
        r.x = lerp_tab(xv.x, table);
        r.y = lerp_tab(xv.y, table);
        r.z = lerp_tab(xv.z, table);
        r.w = lerp_tab(xv.w, table);
        ((float4*)out)[i4] = r;
    } else {
        for (int i = base; i < n; ++i) out[i] = lerp_tab(x[i], table);
    }
}

extern "C" void kernel_launch(void* const* d_in, const int* in_sizes, int n_in,
                              void* d_out, int out_size, void* d_ws, size_t ws_size,
                              hipStream_t stream) {
    const float* x     = (const float*)d_in[0];
    const float* w_ih1 = (const float*)d_in[1];
    // d_in[2] = w_hh1 (unused: h_prev = 0)
    const float* b_ih1 = (const float*)d_in[3];
    const float* b_hh1 = (const float*)d_in[4];
    const float* w_ih2 = (const float*)d_in[5];
    // d_in[6] = w_hh2 (unused)
    const float* b_ih2 = (const float*)d_in[7];
    const float* b_hh2 = (const float*)d_in[8];
    const float* w_lin = (const float*)d_in[9];
    const float* b_lin = (const float*)d_in[10];

    float* out = (float*)d_out;
    // d_ws layout (dwords): [0,16384) table | [16384, 16384+3978) packed W2 | then 153 bias sums
    float*        table = (float*)d_ws;
    unsigned int* Wp    = (unsigned int*)d_ws + 16384;
    float*        B2    = (float*)d_ws + 16384 + 153 * 26;
    const int n = in_sizes[0];     // T*B = 409600

    repack<<<(153 * 26 + 255) / 256, 256, 0, stream>>>(w_ih2, b_ih2, b_hh2, Wp, B2);

    build_table<<<NTAB / 64, 1024, 0, stream>>>(
        w_ih1, b_ih1, b_hh1, Wp, B2, w_lin, b_lin, table);

    const int n4 = (n + 3) / 4;
    lookup_kernel<<<(n4 + 255) / 256, 256, 0, stream>>>(x, table, out, n);
}